// Round 2
// baseline (542.819 us; speedup 1.0000x reference)
//
#include <hip/hip_runtime.h>
#include <hip/hip_bf16.h>

#define NEDGE 262144
#define DIM 256
#define NLAYER 3
#define EPSV 1e-5f
#define BM 128
#define BKK 32
#define LDP 40  // padded LDS row length in bf16 elems (80 B stride -> 2-way bank alias, free)

typedef __attribute__((ext_vector_type(8))) short bf16x8_t;
typedef __attribute__((ext_vector_type(4))) float f32x4_t;

__device__ __forceinline__ float bf2f(short s) {
  unsigned u = ((unsigned)(unsigned short)s) << 16;
  return __builtin_bit_cast(float, u);
}
__device__ __forceinline__ short f2bf(float f) {
  __hip_bfloat16 h = __float2bfloat16(f);
  return __builtin_bit_cast(short, h);
}

// ---------------- Kernel 0: convert Ws (fp32) -> bf16 ----------------
extern "C" __global__ void __launch_bounds__(256)
k_cvt(const float* __restrict__ src, short* __restrict__ dst, int n) {
  int i = blockIdx.x * 256 + threadIdx.x;
  if (i < n) dst[i] = f2bf(src[i]);
}

// ---------------- Kernel 1: h0 = LN(x[src] + x[dst]) ----------------
// one wave per edge, 4 edges per block
extern "C" __global__ void __launch_bounds__(256)
k_edge_ln(const float* __restrict__ x, const int* __restrict__ ei,
          const float* __restrict__ lnw, short* __restrict__ h0) {
  const int e = (blockIdx.x << 2) + (threadIdx.x >> 6);
  const int lane = threadIdx.x & 63;
  const int src = ei[e];
  const int dst = ei[NEDGE + e];
  const float4 a = *(const float4*)(x + (size_t)src * DIM + lane * 4);
  const float4 b = *(const float4*)(x + (size_t)dst * DIM + lane * 4);
  const float v0 = a.x + b.x, v1 = a.y + b.y, v2 = a.z + b.z, v3 = a.w + b.w;
  float s = v0 + v1 + v2 + v3;
  float ss = v0 * v0 + v1 * v1 + v2 * v2 + v3 * v3;
#pragma unroll
  for (int off = 32; off >= 1; off >>= 1) {
    s += __shfl_xor(s, off);
    ss += __shfl_xor(ss, off);
  }
  const float mu = s * (1.0f / DIM);
  const float var = ss * (1.0f / DIM) - mu * mu;
  const float sc = rsqrtf(var + EPSV);
  const float4 w = *(const float4*)(lnw + lane * 4);
  ushort4 o;
  o.x = (unsigned short)f2bf((v0 - mu) * sc * w.x);
  o.y = (unsigned short)f2bf((v1 - mu) * sc * w.y);
  o.z = (unsigned short)f2bf((v2 - mu) * sc * w.z);
  o.w = (unsigned short)f2bf((v3 - mu) * sc * w.w);
  *(ushort4*)(h0 + (size_t)e * DIM + lane * 4) = o;
}

// ---------------- Kernel 2: C[E,256] = act(A) @ W^T, + column partial stats ----
// act(A) = relu(A*bsc + bsh) if bsc != null (BN+ReLU of previous layer), else A.
// IN-PLACE SAFE (C may == A): each block reads only its own BM rows, all reads
// complete (staged through LDS across the K-loop) before the epilogue writes
// those same rows; blocks touch disjoint rows.
// Tile: BM=128 rows x all 256 cols. 4 waves; wave w owns cols [w*64, w*64+64).
extern "C" __global__ void __launch_bounds__(256)
k_gemm(const short* __restrict__ A, const short* __restrict__ W,
       short* __restrict__ C, float* __restrict__ psum, float* __restrict__ psq,
       const float* __restrict__ bsc, const float* __restrict__ bsh) {
  __shared__ short As[BM * LDP];
  __shared__ short Bs[DIM * LDP];
  const int tid = threadIdx.x;
  const int wave = tid >> 6;
  const int lane = tid & 63;
  const int row0 = blockIdx.x * BM;

  const f32x4_t zero = {0.0f, 0.0f, 0.0f, 0.0f};
  f32x4_t acc[8][4];
#pragma unroll
  for (int m = 0; m < 8; ++m)
#pragma unroll
    for (int n = 0; n < 4; ++n) acc[m][n] = zero;

  const int rl = lane & 15;
  const int kl = (lane >> 4) << 3;  // k offset of this lane's fragment

  for (int k0 = 0; k0 < DIM; k0 += BKK) {
    // stage A tile (128 x 32 bf16): 512 units of 16 B, 2 per thread
#pragma unroll
    for (int i = 0; i < 2; ++i) {
      const int u = tid + i * 256;
      const int r = u >> 2, seg = u & 3;
      const int c0 = k0 + (seg << 3);
      bf16x8_t v = *(const bf16x8_t*)(A + (size_t)(row0 + r) * DIM + c0);
      if (bsc != nullptr) {
        bf16x8_t t;
#pragma unroll
        for (int j = 0; j < 8; ++j) {
          float f = bf2f(v[j]);
          f = fmaxf(f * bsc[c0 + j] + bsh[c0 + j], 0.0f);
          t[j] = f2bf(f);
        }
        v = t;
      }
      *(bf16x8_t*)(&As[r * LDP + (seg << 3)]) = v;
    }
    // stage B tile (256 x 32 bf16): 1024 units, 4 per thread
#pragma unroll
    for (int i = 0; i < 4; ++i) {
      const int u = tid + i * 256;
      const int r = u >> 2, seg = u & 3;
      *(bf16x8_t*)(&Bs[r * LDP + (seg << 3)]) =
          *(const bf16x8_t*)(W + r * DIM + k0 + (seg << 3));
    }
    __syncthreads();

    bf16x8_t af[8], bfr[4];
#pragma unroll
    for (int m = 0; m < 8; ++m)
      af[m] = *(const bf16x8_t*)(&As[(m * 16 + rl) * LDP + kl]);
#pragma unroll
    for (int n = 0; n < 4; ++n)
      bfr[n] = *(const bf16x8_t*)(&Bs[(wave * 64 + n * 16 + rl) * LDP + kl]);
#pragma unroll
    for (int m = 0; m < 8; ++m)
#pragma unroll
      for (int n = 0; n < 4; ++n)
        acc[m][n] = __builtin_amdgcn_mfma_f32_16x16x32_bf16(af[m], bfr[n], acc[m][n], 0, 0, 0);
    __syncthreads();
  }

  // epilogue: write raw C (bf16) + per-block column sum / sumsq (deterministic)
  const int rquad = (lane >> 4) << 2;
#pragma unroll
  for (int n = 0; n < 4; ++n) {
    const int col = wave * 64 + n * 16 + rl;
    float s = 0.0f, sq = 0.0f;
#pragma unroll
    for (int m = 0; m < 8; ++m) {
      const size_t rb = (size_t)(row0 + m * 16 + rquad) * DIM + col;
#pragma unroll
      for (int r = 0; r < 4; ++r) {
        const float f = acc[m][n][r];
        C[rb + (size_t)r * DIM] = f2bf(f);
        s += f;
        sq += f * f;
      }
    }
    s += __shfl_xor(s, 16);
    s += __shfl_xor(s, 32);
    sq += __shfl_xor(sq, 16);
    sq += __shfl_xor(sq, 32);
    if (lane < 16) {
      psum[(size_t)blockIdx.x * DIM + col] = s;
      psq[(size_t)blockIdx.x * DIM + col] = sq;
    }
  }
}

// ---------------- Kernel 3: finalize batch stats -> scale/shift --------------
extern "C" __global__ void __launch_bounds__(64)
k_stats(const float* __restrict__ psum, const float* __restrict__ psq,
        const float* __restrict__ gamma, const float* __restrict__ beta,
        float* __restrict__ sc, float* __restrict__ sh, int nblk) {
  const int c = blockIdx.x;
  const int lane = threadIdx.x;
  float s = 0.0f, q = 0.0f;
  for (int b = lane; b < nblk; b += 64) {
    s += psum[(size_t)b * DIM + c];
    q += psq[(size_t)b * DIM + c];
  }
#pragma unroll
  for (int off = 32; off >= 1; off >>= 1) {
    s += __shfl_xor(s, off);
    q += __shfl_xor(q, off);
  }
  if (lane == 0) {
    const float inv = 1.0f / NEDGE;
    const float mu = s * inv;
    const float var = q * inv - mu * mu;
    const float scale = rsqrtf(var + EPSV) * gamma[c];
    sc[c] = scale;
    sh[c] = beta[c] - mu * scale;
  }
}

// ---------------- Kernel 4: logits = relu(bn3(h3)) . w_out ------------------
extern "C" __global__ void __launch_bounds__(256)
k_head(const short* __restrict__ h3, const float* __restrict__ sc,
       const float* __restrict__ sh, const float* __restrict__ wout,
       float* __restrict__ out) {
  const int e = (blockIdx.x << 2) + (threadIdx.x >> 6);
  const int lane = threadIdx.x & 63;
  const ushort4 v = *(const ushort4*)(h3 + (size_t)e * DIM + lane * 4);
  const int c = lane * 4;
  float acc = fmaxf(bf2f((short)v.x) * sc[c + 0] + sh[c + 0], 0.0f) * wout[c + 0];
  acc += fmaxf(bf2f((short)v.y) * sc[c + 1] + sh[c + 1], 0.0f) * wout[c + 1];
  acc += fmaxf(bf2f((short)v.z) * sc[c + 2] + sh[c + 2], 0.0f) * wout[c + 2];
  acc += fmaxf(bf2f((short)v.w) * sc[c + 3] + sh[c + 3], 0.0f) * wout[c + 3];
#pragma unroll
  for (int off = 32; off >= 1; off >>= 1) acc += __shfl_xor(acc, off);
  if (lane == 0) out[e] = acc;
}

extern "C" void kernel_launch(void* const* d_in, const int* in_sizes, int n_in,
                              void* d_out, int out_size, void* d_ws, size_t ws_size,
                              hipStream_t stream) {
  const float* x = (const float*)d_in[0];
  const int* ei = (const int*)d_in[1];
  const float* lnw = (const float*)d_in[2];
  const float* Ws = (const float*)d_in[3];
  const float* gammas = (const float*)d_in[4];
  const float* betas = (const float*)d_in[5];
  const float* wout = (const float*)d_in[6];
  float* out = (float*)d_out;

  // Workspace layout (single in-place h buffer; total ~133 MB):
  //   h   : NEDGE*DIM bf16           = 128 MB
  //   Wb  : NLAYER*DIM*DIM bf16      = 384 KB
  //   psum: (NEDGE/BM)*DIM f32       = 2 MB
  //   psq : (NEDGE/BM)*DIM f32       = 2 MB
  //   bnsc/bnsh: NLAYER*DIM f32 each = 6 KB
  char* ws = (char*)d_ws;
  const size_t HBYTES = (size_t)NEDGE * DIM * 2;
  short* h = (short*)ws;
  short* Wb = (short*)(ws + HBYTES);
  char* p = ws + HBYTES + (size_t)NLAYER * DIM * DIM * 2;
  float* psum = (float*)p;
  float* psq = psum + (size_t)(NEDGE / BM) * DIM;
  float* bnsc = psq + (size_t)(NEDGE / BM) * DIM;
  float* bnsh = bnsc + NLAYER * DIM;

  k_cvt<<<(NLAYER * DIM * DIM + 255) / 256, 256, 0, stream>>>(Ws, Wb, NLAYER * DIM * DIM);
  k_edge_ln<<<NEDGE / 4, 256, 0, stream>>>(x, ei, lnw, h);

  for (int l = 0; l < NLAYER; ++l) {
    const float* sc = (l == 0) ? nullptr : bnsc + (size_t)(l - 1) * DIM;
    const float* sh = (l == 0) ? nullptr : bnsh + (size_t)(l - 1) * DIM;
    k_gemm<<<NEDGE / BM, 256, 0, stream>>>(h, Wb + (size_t)l * DIM * DIM, h,
                                           psum, psq, sc, sh);
    k_stats<<<DIM, 64, 0, stream>>>(psum, psq, gammas + (size_t)l * DIM,
                                    betas + (size_t)l * DIM,
                                    bnsc + (size_t)l * DIM, bnsh + (size_t)l * DIM,
                                    NEDGE / BM);
  }
  k_head<<<NEDGE / 4, 256, 0, stream>>>(h, bnsc + (size_t)(NLAYER - 1) * DIM,
                                        bnsh + (size_t)(NLAYER - 1) * DIM, wout, out);
}

// Round 3
// 310.101 us; speedup vs baseline: 1.7505x; 1.7505x over previous
//
#include <hip/hip_runtime.h>
#include <hip/hip_bf16.h>

#define NEDGE 262144
#define DIM 256
#define NLAYER 3
#define EPSV 1e-5f

#define GBM 512                 // rows per GEMM block
#define RC 64                   // rows per chunk
#define NCH (GBM / RC)          // 8 chunks per block
#define GEMM_GRID (NEDGE / GBM) // 512 blocks

typedef __attribute__((ext_vector_type(8))) short bf16x8_t;
typedef __attribute__((ext_vector_type(4))) float f32x4_t;

__device__ __forceinline__ float bf2f(short s) {
  unsigned u = ((unsigned)(unsigned short)s) << 16;
  return __builtin_bit_cast(float, u);
}
__device__ __forceinline__ short f2bf(float f) {
  __hip_bfloat16 h = __float2bfloat16(f);
  return __builtin_bit_cast(short, h);
}

// ---------------- Kernel 0: convert Ws (fp32) -> bf16 ----------------
extern "C" __global__ void __launch_bounds__(256)
k_cvt(const float* __restrict__ src, short* __restrict__ dst, int n) {
  int i = blockIdx.x * 256 + threadIdx.x;
  if (i < n) dst[i] = f2bf(src[i]);
}

// ---------------- Kernel 1: h0 = LN(x[src] + x[dst]) ----------------
extern "C" __global__ void __launch_bounds__(256)
k_edge_ln(const float* __restrict__ x, const int* __restrict__ ei,
          const float* __restrict__ lnw, short* __restrict__ h0) {
  const int e = (blockIdx.x << 2) + (threadIdx.x >> 6);
  const int lane = threadIdx.x & 63;
  const int src = ei[e];
  const int dst = ei[NEDGE + e];
  const float4 a = *(const float4*)(x + (size_t)src * DIM + lane * 4);
  const float4 b = *(const float4*)(x + (size_t)dst * DIM + lane * 4);
  const float v0 = a.x + b.x, v1 = a.y + b.y, v2 = a.z + b.z, v3 = a.w + b.w;
  float s = v0 + v1 + v2 + v3;
  float ss = v0 * v0 + v1 * v1 + v2 * v2 + v3 * v3;
#pragma unroll
  for (int off = 32; off >= 1; off >>= 1) {
    s += __shfl_xor(s, off);
    ss += __shfl_xor(ss, off);
  }
  const float mu = s * (1.0f / DIM);
  const float var = ss * (1.0f / DIM) - mu * mu;
  const float sc = rsqrtf(var + EPSV);
  const float4 w = *(const float4*)(lnw + lane * 4);
  ushort4 o;
  o.x = (unsigned short)f2bf((v0 - mu) * sc * w.x);
  o.y = (unsigned short)f2bf((v1 - mu) * sc * w.y);
  o.z = (unsigned short)f2bf((v2 - mu) * sc * w.z);
  o.w = (unsigned short)f2bf((v3 - mu) * sc * w.w);
  *(ushort4*)(h0 + (size_t)e * DIM + lane * 4) = o;
}

// -------- Kernel 2: persistent row-streamer GEMM: C = act(A) @ W^T + stats ---
// 8 waves x 512 threads. Wave w owns output cols [w*32, w*32+32); its W
// fragment (32 cols x 256 K) lives in 64 VGPRs, loaded once. A is streamed in
// 64-row chunks through double-buffered LDS with XOR-swizzle (chunk ^= row&7)
// to kill the stride-512B bank conflict. Layer 1: global_load_lds direct with
// pre-swizzled global source. BN layers: reg-stage (load t+2 early / transform
// + ds_write t+1 late) so HBM/L3 latency hides under compute(t).
// In-place safe: block reads & writes only rows [blk*512, +512).
template <int HASBN>
__global__ void __launch_bounds__(512, 2)
k_gemm_p(const short* __restrict__ A, const short* __restrict__ W,
         short* __restrict__ C, float* __restrict__ psum, float* __restrict__ psq,
         const float* __restrict__ bsc, const float* __restrict__ bsh) {
  __shared__ short As[2][RC * DIM];  // 2 x 32 KB
  const int tid = threadIdx.x;
  const int w = tid >> 6;
  const int lane = tid & 63;
  const int rl = lane & 15;
  const int kh = lane >> 4;  // 0..3
  const int row0 = blockIdx.x * GBM;
  const int colbase = w * 32;

  // W fragments (loop-invariant): wf[n][ks], lane holds W[col][ks*32+kh*8 ..+8]
  bf16x8_t wf[2][8];
#pragma unroll
  for (int n = 0; n < 2; ++n)
#pragma unroll
    for (int ks = 0; ks < 8; ++ks)
      wf[n][ks] = *(const bf16x8_t*)(W + (size_t)(colbase + n * 16 + rl) * DIM + ks * 32 + kh * 8);

  // BN constants for this thread's fixed staging column group (c = tid&31)
  const int cst = tid & 31;
  float sc0[8], sh0[8];
  if (HASBN) {
#pragma unroll
    for (int j = 0; j < 8; ++j) {
      sc0[j] = bsc[cst * 8 + j];
      sh0[j] = bsh[cst * 8 + j];
    }
  }

  float st_s0 = 0.f, st_s1 = 0.f, st_q0 = 0.f, st_q1 = 0.f;

  // ---- staging: layer-1 path (async global->LDS, swizzled source) ----
  auto stage_lds = [&](int t, int b) {
#pragma unroll
    for (int i = 0; i < 4; ++i) {
      const int r_lo = w * 8 + i * 2;
      const int row = r_lo + (lane >> 5);
      const int c = lane & 31;
      const short* gp = A + (size_t)(row0 + t * RC + row) * DIM + ((c ^ (row & 7)) << 3);
      short* lp = &As[b][r_lo * DIM];
      __builtin_amdgcn_global_load_lds(
          (const __attribute__((address_space(1))) unsigned int*)gp,
          (__attribute__((address_space(3))) unsigned int*)lp, 16, 0, 0);
    }
  };

  // ---- staging: BN path (reg-stage + transform + swizzled ds_write) ----
  auto ldreg = [&](int t, bf16x8_t* r) {
#pragma unroll
    for (int i = 0; i < 4; ++i) {
      const int row = (tid + i * 512) >> 5;
      r[i] = *(const bf16x8_t*)(A + (size_t)(row0 + t * RC + row) * DIM + cst * 8);
    }
  };
  auto xform_write = [&](int b, bf16x8_t* r) {
#pragma unroll
    for (int i = 0; i < 4; ++i) {
      const int row = (tid + i * 512) >> 5;
      bf16x8_t v = r[i];
      bf16x8_t o;
#pragma unroll
      for (int j = 0; j < 8; ++j)
        o[j] = f2bf(fmaxf(fmaf(bf2f(v[j]), sc0[j], sh0[j]), 0.0f));
      *(bf16x8_t*)(&As[b][row * DIM + ((cst ^ (row & 7)) << 3)]) = o;
    }
  };

  // ---- compute one 64-row chunk ----
  auto compute = [&](int t, int b) {
    const f32x4_t zero = {0.f, 0.f, 0.f, 0.f};
    f32x4_t acc[4][2];
#pragma unroll
    for (int m = 0; m < 4; ++m) {
      acc[m][0] = zero;
      acc[m][1] = zero;
    }
    const short* base = As[b];
#pragma unroll
    for (int ks = 0; ks < 8; ++ks) {
      bf16x8_t af[4];
#pragma unroll
      for (int m = 0; m < 4; ++m) {
        const int row = m * 16 + rl;
        const int c = ks * 4 + kh;
        af[m] = *(const bf16x8_t*)(base + row * DIM + ((c ^ (row & 7)) << 3));
      }
#pragma unroll
      for (int m = 0; m < 4; ++m) {
        acc[m][0] = __builtin_amdgcn_mfma_f32_16x16x32_bf16(af[m], wf[0][ks], acc[m][0], 0, 0, 0);
        acc[m][1] = __builtin_amdgcn_mfma_f32_16x16x32_bf16(af[m], wf[1][ks], acc[m][1], 0, 0, 0);
      }
    }
    // epilogue: write C (bf16) + accumulate column stats in regs
    const int rquad = kh << 2;
#pragma unroll
    for (int n = 0; n < 2; ++n) {
      const int col = colbase + n * 16 + rl;
      float s = 0.f, q = 0.f;
#pragma unroll
      for (int m = 0; m < 4; ++m) {
        const size_t rb = (size_t)(row0 + t * RC + m * 16 + rquad) * DIM + col;
#pragma unroll
        for (int r = 0; r < 4; ++r) {
          const float f = acc[m][n][r];
          C[rb + (size_t)r * DIM] = f2bf(f);
          s += f;
          q = fmaf(f, f, q);
        }
      }
      if (n == 0) { st_s0 += s; st_q0 += q; }
      else        { st_s1 += s; st_q1 += q; }
    }
  };

  if (HASBN == 0) {
    stage_lds(0, 0);
    for (int t = 0; t < NCH; ++t) {
      __syncthreads();  // buf[t&1] staged; prev compute done
      if (t + 1 < NCH) stage_lds(t + 1, (t + 1) & 1);
      compute(t, t & 1);
    }
  } else {
    bf16x8_t ra[4], rb[4];
    ldreg(0, ra);
    xform_write(0, ra);  // chunk 0 -> buf0 (one-time serial wait)
    ldreg(1, rb);
    __syncthreads();
    for (int t = 0; t < NCH; ++t) {
      if (t + 2 < NCH) ldreg(t + 2, ra);        // issue early (hidden by compute)
      compute(t, t & 1);
      if (t + 1 < NCH) xform_write((t + 1) & 1, rb);  // write late
      __syncthreads();
#pragma unroll
      for (int i = 0; i < 4; ++i) { bf16x8_t tmp = ra[i]; ra[i] = rb[i]; rb[i] = tmp; }
    }
  }

  // block-level stats: reduce the 4 row-quad lanes sharing each col
  {
    float s = st_s0, q = st_q0;
    s += __shfl_xor(s, 16); s += __shfl_xor(s, 32);
    q += __shfl_xor(q, 16); q += __shfl_xor(q, 32);
    if (lane < 16) {
      psum[(size_t)blockIdx.x * DIM + colbase + rl] = s;
      psq [(size_t)blockIdx.x * DIM + colbase + rl] = q;
    }
  }
  {
    float s = st_s1, q = st_q1;
    s += __shfl_xor(s, 16); s += __shfl_xor(s, 32);
    q += __shfl_xor(q, 16); q += __shfl_xor(q, 32);
    if (lane < 16) {
      psum[(size_t)blockIdx.x * DIM + colbase + 16 + rl] = s;
      psq [(size_t)blockIdx.x * DIM + colbase + 16 + rl] = q;
    }
  }
}

// ---------------- Kernel 3: finalize batch stats -> scale/shift --------------
extern "C" __global__ void __launch_bounds__(64)
k_stats(const float* __restrict__ psum, const float* __restrict__ psq,
        const float* __restrict__ gamma, const float* __restrict__ beta,
        float* __restrict__ sc, float* __restrict__ sh, int nblk) {
  const int c = blockIdx.x;
  const int lane = threadIdx.x;
  float s = 0.0f, q = 0.0f;
  for (int b = lane; b < nblk; b += 64) {
    s += psum[(size_t)b * DIM + c];
    q += psq[(size_t)b * DIM + c];
  }
#pragma unroll
  for (int off = 32; off >= 1; off >>= 1) {
    s += __shfl_xor(s, off);
    q += __shfl_xor(q, off);
  }
  if (lane == 0) {
    const float inv = 1.0f / NEDGE;
    const float mu = s * inv;
    const float var = q * inv - mu * mu;
    const float scale = rsqrtf(var + EPSV) * gamma[c];
    sc[c] = scale;
    sh[c] = beta[c] - mu * scale;
  }
}

// ---------------- Kernel 4: logits = relu(bn3(h3)) . w_out ------------------
extern "C" __global__ void __launch_bounds__(256)
k_head(const short* __restrict__ h3, const float* __restrict__ sc,
       const float* __restrict__ sh, const float* __restrict__ wout,
       float* __restrict__ out) {
  const int e = (blockIdx.x << 2) + (threadIdx.x >> 6);
  const int lane = threadIdx.x & 63;
  const ushort4 v = *(const ushort4*)(h3 + (size_t)e * DIM + lane * 4);
  const int c = lane * 4;
  float acc = fmaxf(bf2f((short)v.x) * sc[c + 0] + sh[c + 0], 0.0f) * wout[c + 0];
  acc += fmaxf(bf2f((short)v.y) * sc[c + 1] + sh[c + 1], 0.0f) * wout[c + 1];
  acc += fmaxf(bf2f((short)v.z) * sc[c + 2] + sh[c + 2], 0.0f) * wout[c + 2];
  acc += fmaxf(bf2f((short)v.w) * sc[c + 3] + sh[c + 3], 0.0f) * wout[c + 3];
#pragma unroll
  for (int off = 32; off >= 1; off >>= 1) acc += __shfl_xor(acc, off);
  if (lane == 0) out[e] = acc;
}

extern "C" void kernel_launch(void* const* d_in, const int* in_sizes, int n_in,
                              void* d_out, int out_size, void* d_ws, size_t ws_size,
                              hipStream_t stream) {
  const float* x = (const float*)d_in[0];
  const int* ei = (const int*)d_in[1];
  const float* lnw = (const float*)d_in[2];
  const float* Ws = (const float*)d_in[3];
  const float* gammas = (const float*)d_in[4];
  const float* betas = (const float*)d_in[5];
  const float* wout = (const float*)d_in[6];
  float* out = (float*)d_out;

  // Workspace (~129.5 MB): h 128MB | Wb 384KB | psum 512KB | psq 512KB | bn 6KB
  char* ws = (char*)d_ws;
  const size_t HBYTES = (size_t)NEDGE * DIM * 2;
  short* h = (short*)ws;
  short* Wb = (short*)(ws + HBYTES);
  char* p = ws + HBYTES + (size_t)NLAYER * DIM * DIM * 2;
  float* psum = (float*)p;
  float* psq = psum + (size_t)GEMM_GRID * DIM;
  float* bnsc = psq + (size_t)GEMM_GRID * DIM;
  float* bnsh = bnsc + NLAYER * DIM;

  k_cvt<<<(NLAYER * DIM * DIM + 255) / 256, 256, 0, stream>>>(Ws, Wb, NLAYER * DIM * DIM);
  k_edge_ln<<<NEDGE / 4, 256, 0, stream>>>(x, ei, lnw, h);

  for (int l = 0; l < NLAYER; ++l) {
    const float* sc = (l == 0) ? nullptr : bnsc + (size_t)(l - 1) * DIM;
    const float* sh = (l == 0) ? nullptr : bnsh + (size_t)(l - 1) * DIM;
    if (l == 0)
      k_gemm_p<0><<<GEMM_GRID, 512, 0, stream>>>(h, Wb + (size_t)l * DIM * DIM, h,
                                                 psum, psq, sc, sh);
    else
      k_gemm_p<1><<<GEMM_GRID, 512, 0, stream>>>(h, Wb + (size_t)l * DIM * DIM, h,
                                                 psum, psq, sc, sh);
    k_stats<<<DIM, 64, 0, stream>>>(psum, psq, gammas + (size_t)l * DIM,
                                    betas + (size_t)l * DIM,
                                    bnsc + (size_t)l * DIM, bnsh + (size_t)l * DIM,
                                    GEMM_GRID);
  }
  k_head<<<NEDGE / 4, 256, 0, stream>>>(h, bnsc + (size_t)(NLAYER - 1) * DIM,
                                        bnsh + (size_t)(NLAYER - 1) * DIM, wout, out);
}

// Round 4
// 267.391 us; speedup vs baseline: 2.0301x; 1.1597x over previous
//
#include <hip/hip_runtime.h>
#include <hip/hip_bf16.h>

#define NEDGE 262144
#define DIM 256
#define NLAYER 3
#define EPSV 1e-5f

#define GBM 512                 // rows per GEMM block
#define RC 64                   // rows per chunk
#define NCH (GBM / RC)          // 8 chunks per block
#define GEMM_GRID (NEDGE / GBM) // 512 blocks

typedef __attribute__((ext_vector_type(8))) short bf16x8_t;
typedef __attribute__((ext_vector_type(4))) float f32x4_t;

__device__ __forceinline__ float bf2f(short s) {
  unsigned u = ((unsigned)(unsigned short)s) << 16;
  return __builtin_bit_cast(float, u);
}
__device__ __forceinline__ short f2bf(float f) {
  __hip_bfloat16 h = __float2bfloat16(f);
  return __builtin_bit_cast(short, h);
}

// ---------------- Kernel 0: convert Ws (fp32) -> bf16 ----------------
extern "C" __global__ void __launch_bounds__(256)
k_cvt(const float* __restrict__ src, short* __restrict__ dst, int n) {
  int i = blockIdx.x * 256 + threadIdx.x;
  if (i < n) dst[i] = f2bf(src[i]);
}

// ======== Kernel 1: FUSED gather+LN+GEMM1:  C = LN(x[s]+x[d]) @ W^T + stats ==
// 8 waves x 512 threads; wave w owns cols [w*32,+32) with W in 64 VGPRs.
// Staging: 32-lane groups gather one edge-row each (2x 1KB fp32), LN-reduce
// in-register, write bf16 XOR-swizzled to double-buffered LDS. Loads for
// chunk t+1 issue before compute(t) so gather latency hides under MFMA.
extern "C" __global__ void __launch_bounds__(512)
k_gemm1f(const float* __restrict__ x, const int* __restrict__ ei,
         const float* __restrict__ lnw, const short* __restrict__ W,
         short* __restrict__ C, float* __restrict__ psum, float* __restrict__ psq) {
  __shared__ short As[2][RC * DIM];  // 2 x 32 KB
  __shared__ int sIdx[GBM], dIdx[GBM];
  const int tid = threadIdx.x;
  const int w = tid >> 6;
  const int lane = tid & 63;
  const int rl = lane & 15;
  const int kh = lane >> 4;
  const int row0 = blockIdx.x * GBM;
  const int colbase = w * 32;
  const int cst = tid & 31;

  // prefetch this block's edge indices into LDS (once)
  sIdx[tid] = ei[row0 + tid];
  dIdx[tid] = ei[NEDGE + row0 + tid];

  // W fragments (loop-invariant)
  bf16x8_t wf[2][8];
#pragma unroll
  for (int n = 0; n < 2; ++n)
#pragma unroll
    for (int ks = 0; ks < 8; ++ks)
      wf[n][ks] = *(const bf16x8_t*)(W + (size_t)(colbase + n * 16 + rl) * DIM + ks * 32 + kh * 8);

  float lw[8];
#pragma unroll
  for (int j = 0; j < 8; ++j) lw[j] = lnw[cst * 8 + j];

  float st_s0 = 0.f, st_s1 = 0.f, st_q0 = 0.f, st_q1 = 0.f;
  float4 rs0[4], rs1[4], rd0[4], rd1[4];

  auto ldgather = [&](int t) {
#pragma unroll
    for (int i = 0; i < 4; ++i) {
      const int r = (tid >> 5) + 16 * i;
      const int s = sIdx[t * RC + r];
      const int d = dIdx[t * RC + r];
      const float* ps = x + (size_t)s * DIM + cst * 8;
      const float* pd = x + (size_t)d * DIM + cst * 8;
      rs0[i] = *(const float4*)ps;
      rs1[i] = *(const float4*)(ps + 4);
      rd0[i] = *(const float4*)pd;
      rd1[i] = *(const float4*)(pd + 4);
    }
  };

  auto lnwrite = [&](int b) {
#pragma unroll
    for (int i = 0; i < 4; ++i) {
      const int r = (tid >> 5) + 16 * i;
      float v[8];
      v[0] = rs0[i].x + rd0[i].x; v[1] = rs0[i].y + rd0[i].y;
      v[2] = rs0[i].z + rd0[i].z; v[3] = rs0[i].w + rd0[i].w;
      v[4] = rs1[i].x + rd1[i].x; v[5] = rs1[i].y + rd1[i].y;
      v[6] = rs1[i].z + rd1[i].z; v[7] = rs1[i].w + rd1[i].w;
      float s = 0.f, ss = 0.f;
#pragma unroll
      for (int j = 0; j < 8; ++j) { s += v[j]; ss = fmaf(v[j], v[j], ss); }
#pragma unroll
      for (int off = 16; off >= 1; off >>= 1) {
        s += __shfl_xor(s, off);
        ss += __shfl_xor(ss, off);
      }
      const float mu = s * (1.0f / DIM);
      const float var = ss * (1.0f / DIM) - mu * mu;
      const float sc = rsqrtf(var + EPSV);
      bf16x8_t o;
#pragma unroll
      for (int j = 0; j < 8; ++j) o[j] = f2bf((v[j] - mu) * sc * lw[j]);
      *(bf16x8_t*)(&As[b][r * DIM + ((cst ^ (r & 7)) << 3)]) = o;
    }
  };

  auto compute = [&](int t, int b) {
    const f32x4_t zero = {0.f, 0.f, 0.f, 0.f};
    f32x4_t acc[4][2];
#pragma unroll
    for (int m = 0; m < 4; ++m) { acc[m][0] = zero; acc[m][1] = zero; }
    const short* base = As[b];
#pragma unroll
    for (int ks = 0; ks < 8; ++ks) {
      bf16x8_t af[4];
#pragma unroll
      for (int m = 0; m < 4; ++m) {
        const int row = m * 16 + rl;
        const int c = ks * 4 + kh;
        af[m] = *(const bf16x8_t*)(base + row * DIM + ((c ^ (row & 7)) << 3));
      }
#pragma unroll
      for (int m = 0; m < 4; ++m) {
        acc[m][0] = __builtin_amdgcn_mfma_f32_16x16x32_bf16(af[m], wf[0][ks], acc[m][0], 0, 0, 0);
        acc[m][1] = __builtin_amdgcn_mfma_f32_16x16x32_bf16(af[m], wf[1][ks], acc[m][1], 0, 0, 0);
      }
    }
    const int rquad = kh << 2;
#pragma unroll
    for (int n = 0; n < 2; ++n) {
      const int col = colbase + n * 16 + rl;
      float s = 0.f, q = 0.f;
#pragma unroll
      for (int m = 0; m < 4; ++m) {
        const size_t rb = (size_t)(row0 + t * RC + m * 16 + rquad) * DIM + col;
#pragma unroll
        for (int r = 0; r < 4; ++r) {
          const float f = acc[m][n][r];
          C[rb + (size_t)r * DIM] = f2bf(f);
          s += f;
          q = fmaf(f, f, q);
        }
      }
      if (n == 0) { st_s0 += s; st_q0 += q; }
      else        { st_s1 += s; st_q1 += q; }
    }
  };

  __syncthreads();  // idx arrays ready
  ldgather(0);
  lnwrite(0);       // chunk 0 -> buf 0 (one-time serial wait)
  __syncthreads();
  for (int t = 0; t < NCH; ++t) {
    if (t + 1 < NCH) ldgather(t + 1);   // issue early — hidden under MFMA
    compute(t, t & 1);
    if (t + 1 < NCH) lnwrite((t + 1) & 1);  // waits loads, transforms, writes
    __syncthreads();
  }

  {
    float s = st_s0, q = st_q0;
    s += __shfl_xor(s, 16); s += __shfl_xor(s, 32);
    q += __shfl_xor(q, 16); q += __shfl_xor(q, 32);
    if (lane < 16) {
      psum[(size_t)blockIdx.x * DIM + colbase + rl] = s;
      psq [(size_t)blockIdx.x * DIM + colbase + rl] = q;
    }
  }
  {
    float s = st_s1, q = st_q1;
    s += __shfl_xor(s, 16); s += __shfl_xor(s, 32);
    q += __shfl_xor(q, 16); q += __shfl_xor(q, 32);
    if (lane < 16) {
      psum[(size_t)blockIdx.x * DIM + colbase + 16 + rl] = s;
      psq [(size_t)blockIdx.x * DIM + colbase + 16 + rl] = q;
    }
  }
}

// -------- Kernel 2: BN-layer GEMM: C = relu(A*bsc+bsh) @ W^T + stats ---------
// In-place safe: block reads & writes only rows [blk*512, +512).
extern "C" __global__ void __launch_bounds__(512, 2)
k_gemm_bn(const short* __restrict__ A, const short* __restrict__ W,
          short* __restrict__ C, float* __restrict__ psum, float* __restrict__ psq,
          const float* __restrict__ bsc, const float* __restrict__ bsh) {
  __shared__ short As[2][RC * DIM];
  const int tid = threadIdx.x;
  const int w = tid >> 6;
  const int lane = tid & 63;
  const int rl = lane & 15;
  const int kh = lane >> 4;
  const int row0 = blockIdx.x * GBM;
  const int colbase = w * 32;

  bf16x8_t wf[2][8];
#pragma unroll
  for (int n = 0; n < 2; ++n)
#pragma unroll
    for (int ks = 0; ks < 8; ++ks)
      wf[n][ks] = *(const bf16x8_t*)(W + (size_t)(colbase + n * 16 + rl) * DIM + ks * 32 + kh * 8);

  const int cst = tid & 31;
  float sc0[8], sh0[8];
#pragma unroll
  for (int j = 0; j < 8; ++j) {
    sc0[j] = bsc[cst * 8 + j];
    sh0[j] = bsh[cst * 8 + j];
  }

  float st_s0 = 0.f, st_s1 = 0.f, st_q0 = 0.f, st_q1 = 0.f;

  auto ldreg = [&](int t, bf16x8_t* r) {
#pragma unroll
    for (int i = 0; i < 4; ++i) {
      const int row = (tid + i * 512) >> 5;
      r[i] = *(const bf16x8_t*)(A + (size_t)(row0 + t * RC + row) * DIM + cst * 8);
    }
  };
  auto xform_write = [&](int b, bf16x8_t* r) {
#pragma unroll
    for (int i = 0; i < 4; ++i) {
      const int row = (tid + i * 512) >> 5;
      bf16x8_t v = r[i];
      bf16x8_t o;
#pragma unroll
      for (int j = 0; j < 8; ++j)
        o[j] = f2bf(fmaxf(fmaf(bf2f(v[j]), sc0[j], sh0[j]), 0.0f));
      *(bf16x8_t*)(&As[b][row * DIM + ((cst ^ (row & 7)) << 3)]) = o;
    }
  };

  auto compute = [&](int t, int b) {
    const f32x4_t zero = {0.f, 0.f, 0.f, 0.f};
    f32x4_t acc[4][2];
#pragma unroll
    for (int m = 0; m < 4; ++m) { acc[m][0] = zero; acc[m][1] = zero; }
    const short* base = As[b];
#pragma unroll
    for (int ks = 0; ks < 8; ++ks) {
      bf16x8_t af[4];
#pragma unroll
      for (int m = 0; m < 4; ++m) {
        const int row = m * 16 + rl;
        const int c = ks * 4 + kh;
        af[m] = *(const bf16x8_t*)(base + row * DIM + ((c ^ (row & 7)) << 3));
      }
#pragma unroll
      for (int m = 0; m < 4; ++m) {
        acc[m][0] = __builtin_amdgcn_mfma_f32_16x16x32_bf16(af[m], wf[0][ks], acc[m][0], 0, 0, 0);
        acc[m][1] = __builtin_amdgcn_mfma_f32_16x16x32_bf16(af[m], wf[1][ks], acc[m][1], 0, 0, 0);
      }
    }
    const int rquad = kh << 2;
#pragma unroll
    for (int n = 0; n < 2; ++n) {
      const int col = colbase + n * 16 + rl;
      float s = 0.f, q = 0.f;
#pragma unroll
      for (int m = 0; m < 4; ++m) {
        const size_t rb = (size_t)(row0 + t * RC + m * 16 + rquad) * DIM + col;
#pragma unroll
        for (int r = 0; r < 4; ++r) {
          const float f = acc[m][n][r];
          C[rb + (size_t)r * DIM] = f2bf(f);
          s += f;
          q = fmaf(f, f, q);
        }
      }
      if (n == 0) { st_s0 += s; st_q0 += q; }
      else        { st_s1 += s; st_q1 += q; }
    }
  };

  bf16x8_t ra[4], rb[4];
  ldreg(0, ra);
  xform_write(0, ra);
  ldreg(1, rb);
  __syncthreads();
  for (int t = 0; t < NCH; ++t) {
    if (t + 2 < NCH) ldreg(t + 2, ra);
    compute(t, t & 1);
    if (t + 1 < NCH) xform_write((t + 1) & 1, rb);
    __syncthreads();
#pragma unroll
    for (int i = 0; i < 4; ++i) { bf16x8_t tmp = ra[i]; ra[i] = rb[i]; rb[i] = tmp; }
  }

  {
    float s = st_s0, q = st_q0;
    s += __shfl_xor(s, 16); s += __shfl_xor(s, 32);
    q += __shfl_xor(q, 16); q += __shfl_xor(q, 32);
    if (lane < 16) {
      psum[(size_t)blockIdx.x * DIM + colbase + rl] = s;
      psq [(size_t)blockIdx.x * DIM + colbase + rl] = q;
    }
  }
  {
    float s = st_s1, q = st_q1;
    s += __shfl_xor(s, 16); s += __shfl_xor(s, 32);
    q += __shfl_xor(q, 16); q += __shfl_xor(q, 32);
    if (lane < 16) {
      psum[(size_t)blockIdx.x * DIM + colbase + 16 + rl] = s;
      psq [(size_t)blockIdx.x * DIM + colbase + 16 + rl] = q;
    }
  }
}

// ---------------- Kernel 3: finalize batch stats -> scale/shift --------------
extern "C" __global__ void __launch_bounds__(64)
k_stats(const float* __restrict__ psum, const float* __restrict__ psq,
        const float* __restrict__ gamma, const float* __restrict__ beta,
        float* __restrict__ sc, float* __restrict__ sh, int nblk) {
  const int c = blockIdx.x;
  const int lane = threadIdx.x;
  float s = 0.0f, q = 0.0f;
  for (int b = lane; b < nblk; b += 64) {
    s += psum[(size_t)b * DIM + c];
    q += psq[(size_t)b * DIM + c];
  }
#pragma unroll
  for (int off = 32; off >= 1; off >>= 1) {
    s += __shfl_xor(s, off);
    q += __shfl_xor(q, off);
  }
  if (lane == 0) {
    const float inv = 1.0f / NEDGE;
    const float mu = s * inv;
    const float var = q * inv - mu * mu;
    const float scale = rsqrtf(var + EPSV) * gamma[c];
    sc[c] = scale;
    sh[c] = beta[c] - mu * scale;
  }
}

// ---------------- Kernel 4: logits = relu(bn3(h3)) . w_out ------------------
// 32-lane groups, 16 B/lane, 8 edges per 256-thread block
extern "C" __global__ void __launch_bounds__(256)
k_head(const short* __restrict__ h3, const float* __restrict__ sc,
       const float* __restrict__ sh, const float* __restrict__ wout,
       float* __restrict__ out) {
  const int e = (blockIdx.x << 3) + (threadIdx.x >> 5);
  const int g = threadIdx.x & 31;
  const int c = g * 8;
  const bf16x8_t v = *(const bf16x8_t*)(h3 + (size_t)e * DIM + c);
  float acc = 0.f;
#pragma unroll
  for (int j = 0; j < 8; ++j)
    acc += fmaxf(fmaf(bf2f(v[j]), sc[c + j], sh[c + j]), 0.0f) * wout[c + j];
#pragma unroll
  for (int off = 16; off >= 1; off >>= 1) acc += __shfl_xor(acc, off);
  if (g == 0) out[e] = acc;
}

extern "C" void kernel_launch(void* const* d_in, const int* in_sizes, int n_in,
                              void* d_out, int out_size, void* d_ws, size_t ws_size,
                              hipStream_t stream) {
  const float* x = (const float*)d_in[0];
  const int* ei = (const int*)d_in[1];
  const float* lnw = (const float*)d_in[2];
  const float* Ws = (const float*)d_in[3];
  const float* gammas = (const float*)d_in[4];
  const float* betas = (const float*)d_in[5];
  const float* wout = (const float*)d_in[6];
  float* out = (float*)d_out;

  // Workspace (~130 MB): h 128MB | Wb 384KB | psum 512KB | psq 512KB | bn 6KB
  char* ws = (char*)d_ws;
  const size_t HBYTES = (size_t)NEDGE * DIM * 2;
  short* h = (short*)ws;
  short* Wb = (short*)(ws + HBYTES);
  char* p = ws + HBYTES + (size_t)NLAYER * DIM * DIM * 2;
  float* psum = (float*)p;
  float* psq = psum + (size_t)GEMM_GRID * DIM;
  float* bnsc = psq + (size_t)GEMM_GRID * DIM;
  float* bnsh = bnsc + NLAYER * DIM;

  k_cvt<<<(NLAYER * DIM * DIM + 255) / 256, 256, 0, stream>>>(Ws, Wb, NLAYER * DIM * DIM);

  // layer 1: fused gather+LN+GEMM
  k_gemm1f<<<GEMM_GRID, 512, 0, stream>>>(x, ei, lnw, Wb, h, psum, psq);
  k_stats<<<DIM, 64, 0, stream>>>(psum, psq, gammas, betas, bnsc, bnsh, GEMM_GRID);

  for (int l = 1; l < NLAYER; ++l) {
    k_gemm_bn<<<GEMM_GRID, 512, 0, stream>>>(h, Wb + (size_t)l * DIM * DIM, h,
                                             psum, psq,
                                             bnsc + (size_t)(l - 1) * DIM,
                                             bnsh + (size_t)(l - 1) * DIM);
    k_stats<<<DIM, 64, 0, stream>>>(psum, psq, gammas + (size_t)l * DIM,
                                    betas + (size_t)l * DIM,
                                    bnsc + (size_t)l * DIM, bnsh + (size_t)l * DIM,
                                    GEMM_GRID);
  }
  k_head<<<NEDGE / 8, 256, 0, stream>>>(h, bnsc + (size_t)(NLAYER - 1) * DIM,
                                        bnsh + (size_t)(NLAYER - 1) * DIM, wout, out);
}

// Round 5
// 259.585 us; speedup vs baseline: 2.0911x; 1.0301x over previous
//
#include <hip/hip_runtime.h>
#include <hip/hip_bf16.h>

#define NEDGE 262144
#define DIM 256
#define NNODE 50000
#define NLAYER 3
#define EPSV 1e-5f

#define GBM 512                 // rows per GEMM block
#define RC 64                   // rows per chunk
#define NCH (GBM / RC)          // 8 chunks per block
#define GEMM_GRID (NEDGE / GBM) // 512 blocks

typedef __attribute__((ext_vector_type(8))) short bf16x8_t;
typedef __attribute__((ext_vector_type(4))) float f32x4_t;

__device__ __forceinline__ float bf2f(short s) {
  unsigned u = ((unsigned)(unsigned short)s) << 16;
  return __builtin_bit_cast(float, u);
}
__device__ __forceinline__ short f2bf(float f) {
  __hip_bfloat16 h = __float2bfloat16(f);
  return __builtin_bit_cast(short, h);
}

// ---------------- Kernel 0a: convert Ws (fp32) -> bf16 ----------------
extern "C" __global__ void __launch_bounds__(256)
k_cvt(const float* __restrict__ src, short* __restrict__ dst, int n) {
  int i = blockIdx.x * 256 + threadIdx.x;
  if (i < n) dst[i] = f2bf(src[i]);
}

// ---------------- Kernel 0b: convert x (fp32) -> bf16, 8 elems/thread -------
extern "C" __global__ void __launch_bounds__(256)
k_cvt_x(const float* __restrict__ src, short* __restrict__ dst, int n8) {
  int i = blockIdx.x * 256 + threadIdx.x;
  if (i >= n8) return;
  const float4 a = *(const float4*)(src + (size_t)i * 8);
  const float4 b = *(const float4*)(src + (size_t)i * 8 + 4);
  bf16x8_t o;
  o[0] = f2bf(a.x); o[1] = f2bf(a.y); o[2] = f2bf(a.z); o[3] = f2bf(a.w);
  o[4] = f2bf(b.x); o[5] = f2bf(b.y); o[6] = f2bf(b.z); o[7] = f2bf(b.w);
  *(bf16x8_t*)(dst + (size_t)i * 8) = o;
}

// ======== Kernel 1: FUSED gather+LN+GEMM1:  C = LN(xb[s]+xb[d]) @ W^T ========
// 8 waves x 512 threads; wave w owns cols [w*32,+32), W in 64 VGPRs.
// Gather from bf16 x-copy: 32-lane group per row, 16 B/lane. 2-deep prefetch
// (chunk t+2 issued before compute(t); per-set waits, never a full drain).
extern "C" __global__ void __launch_bounds__(512)
k_gemm1f(const short* __restrict__ xb, const int* __restrict__ ei,
         const float* __restrict__ lnw, const short* __restrict__ W,
         short* __restrict__ C, float* __restrict__ psum, float* __restrict__ psq) {
  __shared__ short As[2][RC * DIM];  // 2 x 32 KB
  __shared__ int sIdx[GBM], dIdx[GBM];
  const int tid = threadIdx.x;
  const int w = tid >> 6;
  const int lane = tid & 63;
  const int rl = lane & 15;
  const int kh = lane >> 4;
  const int row0 = blockIdx.x * GBM;
  const int colbase = w * 32;
  const int cst = tid & 31;

  sIdx[tid] = ei[row0 + tid];
  dIdx[tid] = ei[NEDGE + row0 + tid];

  bf16x8_t wf[2][8];
#pragma unroll
  for (int n = 0; n < 2; ++n)
#pragma unroll
    for (int ks = 0; ks < 8; ++ks)
      wf[n][ks] = *(const bf16x8_t*)(W + (size_t)(colbase + n * 16 + rl) * DIM + ks * 32 + kh * 8);

  float lw[8];
#pragma unroll
  for (int j = 0; j < 8; ++j) lw[j] = lnw[cst * 8 + j];

  float st_s0 = 0.f, st_s1 = 0.f, st_q0 = 0.f, st_q1 = 0.f;

  // two named staging sets (even chunks -> A, odd -> B); 32 VGPR each
  bf16x8_t rsA[4], rdA[4], rsB[4], rdB[4];

  auto ldgA = [&](int t) {
#pragma unroll
    for (int i = 0; i < 4; ++i) {
      const int r = (tid >> 5) + 16 * i;
      const int s = sIdx[t * RC + r];
      const int d = dIdx[t * RC + r];
      rsA[i] = *(const bf16x8_t*)(xb + (size_t)s * DIM + cst * 8);
      rdA[i] = *(const bf16x8_t*)(xb + (size_t)d * DIM + cst * 8);
    }
  };
  auto ldgB = [&](int t) {
#pragma unroll
    for (int i = 0; i < 4; ++i) {
      const int r = (tid >> 5) + 16 * i;
      const int s = sIdx[t * RC + r];
      const int d = dIdx[t * RC + r];
      rsB[i] = *(const bf16x8_t*)(xb + (size_t)s * DIM + cst * 8);
      rdB[i] = *(const bf16x8_t*)(xb + (size_t)d * DIM + cst * 8);
    }
  };

  auto lnwr = [&](int b, bf16x8_t* rs, bf16x8_t* rd) {
#pragma unroll
    for (int i = 0; i < 4; ++i) {
      const int r = (tid >> 5) + 16 * i;
      float v[8];
#pragma unroll
      for (int j = 0; j < 8; ++j) v[j] = bf2f(rs[i][j]) + bf2f(rd[i][j]);
      float s = 0.f, ss = 0.f;
#pragma unroll
      for (int j = 0; j < 8; ++j) { s += v[j]; ss = fmaf(v[j], v[j], ss); }
#pragma unroll
      for (int off = 16; off >= 1; off >>= 1) {
        s += __shfl_xor(s, off);
        ss += __shfl_xor(ss, off);
      }
      const float mu = s * (1.0f / DIM);
      const float var = ss * (1.0f / DIM) - mu * mu;
      const float sc = rsqrtf(var + EPSV);
      bf16x8_t o;
#pragma unroll
      for (int j = 0; j < 8; ++j) o[j] = f2bf((v[j] - mu) * sc * lw[j]);
      *(bf16x8_t*)(&As[b][r * DIM + ((cst ^ (r & 7)) << 3)]) = o;
    }
  };

  auto compute = [&](int t, int b) {
    const f32x4_t zero = {0.f, 0.f, 0.f, 0.f};
    f32x4_t acc[4][2];
#pragma unroll
    for (int m = 0; m < 4; ++m) { acc[m][0] = zero; acc[m][1] = zero; }
    const short* base = As[b];
#pragma unroll
    for (int ks = 0; ks < 8; ++ks) {
      bf16x8_t af[4];
#pragma unroll
      for (int m = 0; m < 4; ++m) {
        const int row = m * 16 + rl;
        const int c = ks * 4 + kh;
        af[m] = *(const bf16x8_t*)(base + row * DIM + ((c ^ (row & 7)) << 3));
      }
#pragma unroll
      for (int m = 0; m < 4; ++m) {
        acc[m][0] = __builtin_amdgcn_mfma_f32_16x16x32_bf16(af[m], wf[0][ks], acc[m][0], 0, 0, 0);
        acc[m][1] = __builtin_amdgcn_mfma_f32_16x16x32_bf16(af[m], wf[1][ks], acc[m][1], 0, 0, 0);
      }
    }
    const int rquad = kh << 2;
#pragma unroll
    for (int n = 0; n < 2; ++n) {
      const int col = colbase + n * 16 + rl;
      float s = 0.f, q = 0.f;
#pragma unroll
      for (int m = 0; m < 4; ++m) {
        const size_t rb = (size_t)(row0 + t * RC + m * 16 + rquad) * DIM + col;
#pragma unroll
        for (int r = 0; r < 4; ++r) {
          const float f = acc[m][n][r];
          C[rb + (size_t)r * DIM] = f2bf(f);
          s += f;
          q = fmaf(f, f, q);
        }
      }
      if (n == 0) { st_s0 += s; st_q0 += q; }
      else        { st_s1 += s; st_q1 += q; }
    }
  };

  __syncthreads();  // idx arrays ready
  ldgA(0);          // chunk 0 -> set A
  ldgB(1);          // chunk 1 -> set B (stays in flight)
  lnwr(0, rsA, rdA);  // waits set A only
  __syncthreads();
  // steady state, unrolled x2: even chunks in A->buf0, odd in B->buf1
  for (int t = 0; t < NCH; t += 2) {
    if (t + 2 < NCH) ldgA(t + 2);      // issue 2 ahead
    compute(t, 0);
    lnwr(1, rsB, rdB);                 // chunk t+1 -> buf1
    __syncthreads();
    if (t + 3 < NCH) ldgB(t + 3);
    compute(t + 1, 1);
    if (t + 2 < NCH) lnwr(0, rsA, rdA);  // chunk t+2 -> buf0
    __syncthreads();
  }

  {
    float s = st_s0, q = st_q0;
    s += __shfl_xor(s, 16); s += __shfl_xor(s, 32);
    q += __shfl_xor(q, 16); q += __shfl_xor(q, 32);
    if (lane < 16) {
      psum[(size_t)blockIdx.x * DIM + colbase + rl] = s;
      psq [(size_t)blockIdx.x * DIM + colbase + rl] = q;
    }
  }
  {
    float s = st_s1, q = st_q1;
    s += __shfl_xor(s, 16); s += __shfl_xor(s, 32);
    q += __shfl_xor(q, 16); q += __shfl_xor(q, 32);
    if (lane < 16) {
      psum[(size_t)blockIdx.x * DIM + colbase + 16 + rl] = s;
      psq [(size_t)blockIdx.x * DIM + colbase + 16 + rl] = q;
    }
  }
}

// -------- Kernel 2: BN-layer GEMM: C = relu(A*bsc+bsh) @ W^T + stats ---------
// In-place safe: block reads & writes only rows [blk*512, +512).
extern "C" __global__ void __launch_bounds__(512, 2)
k_gemm_bn(const short* __restrict__ A, const short* __restrict__ W,
          short* __restrict__ C, float* __restrict__ psum, float* __restrict__ psq,
          const float* __restrict__ bsc, const float* __restrict__ bsh) {
  __shared__ short As[2][RC * DIM];
  const int tid = threadIdx.x;
  const int w = tid >> 6;
  const int lane = tid & 63;
  const int rl = lane & 15;
  const int kh = lane >> 4;
  const int row0 = blockIdx.x * GBM;
  const int colbase = w * 32;

  bf16x8_t wf[2][8];
#pragma unroll
  for (int n = 0; n < 2; ++n)
#pragma unroll
    for (int ks = 0; ks < 8; ++ks)
      wf[n][ks] = *(const bf16x8_t*)(W + (size_t)(colbase + n * 16 + rl) * DIM + ks * 32 + kh * 8);

  const int cst = tid & 31;
  float sc0[8], sh0[8];
#pragma unroll
  for (int j = 0; j < 8; ++j) {
    sc0[j] = bsc[cst * 8 + j];
    sh0[j] = bsh[cst * 8 + j];
  }

  float st_s0 = 0.f, st_s1 = 0.f, st_q0 = 0.f, st_q1 = 0.f;

  auto ldreg = [&](int t, bf16x8_t* r) {
#pragma unroll
    for (int i = 0; i < 4; ++i) {
      const int row = (tid + i * 512) >> 5;
      r[i] = *(const bf16x8_t*)(A + (size_t)(row0 + t * RC + row) * DIM + cst * 8);
    }
  };
  auto xform_write = [&](int b, bf16x8_t* r) {
#pragma unroll
    for (int i = 0; i < 4; ++i) {
      const int row = (tid + i * 512) >> 5;
      bf16x8_t v = r[i];
      bf16x8_t o;
#pragma unroll
      for (int j = 0; j < 8; ++j)
        o[j] = f2bf(fmaxf(fmaf(bf2f(v[j]), sc0[j], sh0[j]), 0.0f));
      *(bf16x8_t*)(&As[b][row * DIM + ((cst ^ (row & 7)) << 3)]) = o;
    }
  };

  auto compute = [&](int t, int b) {
    const f32x4_t zero = {0.f, 0.f, 0.f, 0.f};
    f32x4_t acc[4][2];
#pragma unroll
    for (int m = 0; m < 4; ++m) { acc[m][0] = zero; acc[m][1] = zero; }
    const short* base = As[b];
#pragma unroll
    for (int ks = 0; ks < 8; ++ks) {
      bf16x8_t af[4];
#pragma unroll
      for (int m = 0; m < 4; ++m) {
        const int row = m * 16 + rl;
        const int c = ks * 4 + kh;
        af[m] = *(const bf16x8_t*)(base + row * DIM + ((c ^ (row & 7)) << 3));
      }
#pragma unroll
      for (int m = 0; m < 4; ++m) {
        acc[m][0] = __builtin_amdgcn_mfma_f32_16x16x32_bf16(af[m], wf[0][ks], acc[m][0], 0, 0, 0);
        acc[m][1] = __builtin_amdgcn_mfma_f32_16x16x32_bf16(af[m], wf[1][ks], acc[m][1], 0, 0, 0);
      }
    }
    const int rquad = kh << 2;
#pragma unroll
    for (int n = 0; n < 2; ++n) {
      const int col = colbase + n * 16 + rl;
      float s = 0.f, q = 0.f;
#pragma unroll
      for (int m = 0; m < 4; ++m) {
        const size_t rb = (size_t)(row0 + t * RC + m * 16 + rquad) * DIM + col;
#pragma unroll
        for (int r = 0; r < 4; ++r) {
          const float f = acc[m][n][r];
          C[rb + (size_t)r * DIM] = f2bf(f);
          s += f;
          q = fmaf(f, f, q);
        }
      }
      if (n == 0) { st_s0 += s; st_q0 += q; }
      else        { st_s1 += s; st_q1 += q; }
    }
  };

  bf16x8_t ra[4], rb[4];
  ldreg(0, ra);
  xform_write(0, ra);
  ldreg(1, rb);
  __syncthreads();
  for (int t = 0; t < NCH; ++t) {
    if (t + 2 < NCH) ldreg(t + 2, ra);
    compute(t, t & 1);
    if (t + 1 < NCH) xform_write((t + 1) & 1, rb);
    __syncthreads();
#pragma unroll
    for (int i = 0; i < 4; ++i) { bf16x8_t tmp = ra[i]; ra[i] = rb[i]; rb[i] = tmp; }
  }

  {
    float s = st_s0, q = st_q0;
    s += __shfl_xor(s, 16); s += __shfl_xor(s, 32);
    q += __shfl_xor(q, 16); q += __shfl_xor(q, 32);
    if (lane < 16) {
      psum[(size_t)blockIdx.x * DIM + colbase + rl] = s;
      psq [(size_t)blockIdx.x * DIM + colbase + rl] = q;
    }
  }
  {
    float s = st_s1, q = st_q1;
    s += __shfl_xor(s, 16); s += __shfl_xor(s, 32);
    q += __shfl_xor(q, 16); q += __shfl_xor(q, 32);
    if (lane < 16) {
      psum[(size_t)blockIdx.x * DIM + colbase + 16 + rl] = s;
      psq [(size_t)blockIdx.x * DIM + colbase + 16 + rl] = q;
    }
  }
}

// ---------------- Kernel 3: finalize batch stats -> scale/shift --------------
extern "C" __global__ void __launch_bounds__(64)
k_stats(const float* __restrict__ psum, const float* __restrict__ psq,
        const float* __restrict__ gamma, const float* __restrict__ beta,
        float* __restrict__ sc, float* __restrict__ sh, int nblk) {
  const int c = blockIdx.x;
  const int lane = threadIdx.x;
  float s = 0.0f, q = 0.0f;
  for (int b = lane; b < nblk; b += 64) {
    s += psum[(size_t)b * DIM + c];
    q += psq[(size_t)b * DIM + c];
  }
#pragma unroll
  for (int off = 32; off >= 1; off >>= 1) {
    s += __shfl_xor(s, off);
    q += __shfl_xor(q, off);
  }
  if (lane == 0) {
    const float inv = 1.0f / NEDGE;
    const float mu = s * inv;
    const float var = q * inv - mu * mu;
    const float scale = rsqrtf(var + EPSV) * gamma[c];
    sc[c] = scale;
    sh[c] = beta[c] - mu * scale;
  }
}

// ---------------- Kernel 4: logits = relu(bn3(h3)) . w_out ------------------
extern "C" __global__ void __launch_bounds__(256)
k_head(const short* __restrict__ h3, const float* __restrict__ sc,
       const float* __restrict__ sh, const float* __restrict__ wout,
       float* __restrict__ out) {
  const int e = (blockIdx.x << 3) + (threadIdx.x >> 5);
  const int g = threadIdx.x & 31;
  const int c = g * 8;
  const bf16x8_t v = *(const bf16x8_t*)(h3 + (size_t)e * DIM + c);
  float acc = 0.f;
#pragma unroll
  for (int j = 0; j < 8; ++j)
    acc += fmaxf(fmaf(bf2f(v[j]), sc[c + j], sh[c + j]), 0.0f) * wout[c + j];
#pragma unroll
  for (int off = 16; off >= 1; off >>= 1) acc += __shfl_xor(acc, off);
  if (g == 0) out[e] = acc;
}

extern "C" void kernel_launch(void* const* d_in, const int* in_sizes, int n_in,
                              void* d_out, int out_size, void* d_ws, size_t ws_size,
                              hipStream_t stream) {
  const float* x = (const float*)d_in[0];
  const int* ei = (const int*)d_in[1];
  const float* lnw = (const float*)d_in[2];
  const float* Ws = (const float*)d_in[3];
  const float* gammas = (const float*)d_in[4];
  const float* betas = (const float*)d_in[5];
  const float* wout = (const float*)d_in[6];
  float* out = (float*)d_out;

  // Workspace (~155 MB): h 128MB | Wb 384KB | psum 512KB | psq 512KB | bn 6KB | xb 25.6MB
  char* ws = (char*)d_ws;
  const size_t HBYTES = (size_t)NEDGE * DIM * 2;
  short* h = (short*)ws;
  short* Wb = (short*)(ws + HBYTES);
  char* p = ws + HBYTES + (size_t)NLAYER * DIM * DIM * 2;
  float* psum = (float*)p;
  float* psq = psum + (size_t)GEMM_GRID * DIM;
  float* bnsc = psq + (size_t)GEMM_GRID * DIM;
  float* bnsh = bnsc + NLAYER * DIM;
  short* xb = (short*)(bnsh + NLAYER * DIM);

  k_cvt<<<(NLAYER * DIM * DIM + 255) / 256, 256, 0, stream>>>(Ws, Wb, NLAYER * DIM * DIM);
  k_cvt_x<<<(NNODE * DIM / 8 + 255) / 256, 256, 0, stream>>>(x, xb, NNODE * DIM / 8);

  // layer 1: fused gather+LN+GEMM
  k_gemm1f<<<GEMM_GRID, 512, 0, stream>>>(xb, ei, lnw, Wb, h, psum, psq);
  k_stats<<<DIM, 64, 0, stream>>>(psum, psq, gammas, betas, bnsc, bnsh, GEMM_GRID);

  for (int l = 1; l < NLAYER; ++l) {
    k_gemm_bn<<<GEMM_GRID, 512, 0, stream>>>(h, Wb + (size_t)l * DIM * DIM, h,
                                             psum, psq,
                                             bnsc + (size_t)(l - 1) * DIM,
                                             bnsh + (size_t)(l - 1) * DIM);
    k_stats<<<DIM, 64, 0, stream>>>(psum, psq, gammas + (size_t)l * DIM,
                                    betas + (size_t)l * DIM,
                                    bnsc + (size_t)l * DIM, bnsh + (size_t)l * DIM,
                                    GEMM_GRID);
  }
  k_head<<<NEDGE / 8, 256, 0, stream>>>(h, bnsc + (size_t)(NLAYER - 1) * DIM,
                                        bnsh + (size_t)(NLAYER - 1) * DIM, wout, out);
}